// Round 2
// baseline (318.434 us; speedup 1.0000x reference)
//
#include <hip/hip_runtime.h>
#include <math.h>

#define B 16
#define S 2048
#define C 1024
#define H 8
#define HD 128
#define NC 64
#define R (S / NC)   // 32 rows per chunk

// ---------------------------------------------------------------------------
// k2: fused qk-precompute + streaming softmax pass.
// Block = one (b, s-chunk). Thread t (0..255): head h = t>>5, float4 col 4t.
// Step A: qv[4] = row-fragment of qk[b,h,:] = sum_e (pref*Wq[e]+bq[e])*Wk[e,:]
//         (q·bk term dropped: softmax shift-invariant)
// Step B: for 32 rows, 4-row batched: dot + 32-lane butterfly -> score,
//         online softmax update of (m, l, a[4]) in registers.
// ---------------------------------------------------------------------------
__global__ __launch_bounds__(256) void k2_pass(
    const float* __restrict__ feat, const float* __restrict__ pref,
    const float* __restrict__ Wq, const float* __restrict__ bq,
    const float* __restrict__ Wk,
    float* __restrict__ pm, float* __restrict__ pl, float* __restrict__ pf) {
    int wg    = blockIdx.x;          // b*NC + chunk
    int b     = wg >> 6;
    int chunk = wg & (NC - 1);
    int t     = threadIdx.x;
    int h     = t >> 5;
    int lane32 = t & 31;

    // --- Step A: qk fragment in registers ---
    float p = pref[b * H + h];
    float4 qv; qv.x = qv.y = qv.z = qv.w = 0.f;
    const float4* Wk4 = (const float4*)Wk;
#pragma unroll 8
    for (int e = 0; e < HD; ++e) {
        float qe = p * Wq[e] + bq[e];
        float4 w = Wk4[e * (HD / 4) + lane32];   // broadcast within half-wave
        qv.x += qe * w.x; qv.y += qe * w.y;
        qv.z += qe * w.z; qv.w += qe * w.w;
    }

    // --- Step B: streaming online softmax over R rows ---
    const float4* frow = (const float4*)feat
                       + (size_t)(b * S + chunk * R) * (C / 4) + t;
    float m = -1e30f, l = 0.f;
    float4 a; a.x = a.y = a.z = a.w = 0.f;

#pragma unroll
    for (int s0 = 0; s0 < R; s0 += 4) {
        float4 f[4]; float sc[4];
#pragma unroll
        for (int j = 0; j < 4; ++j)
            f[j] = frow[(size_t)(s0 + j) * (C / 4)];
#pragma unroll
        for (int j = 0; j < 4; ++j) {
            float part = f[j].x * qv.x + f[j].y * qv.y
                       + f[j].z * qv.z + f[j].w * qv.w;
            part += __shfl_xor(part, 16, 32);
            part += __shfl_xor(part, 8, 32);
            part += __shfl_xor(part, 4, 32);
            part += __shfl_xor(part, 2, 32);
            part += __shfl_xor(part, 1, 32);
            sc[j] = part;
        }
#pragma unroll
        for (int j = 0; j < 4; ++j) {
            float mn    = fmaxf(m, sc[j]);
            float scale = __expf(m - mn);
            float pw    = __expf(sc[j] - mn);
            l   = l * scale + pw;
            a.x = a.x * scale + pw * f[j].x;
            a.y = a.y * scale + pw * f[j].y;
            a.z = a.z * scale + pw * f[j].z;
            a.w = a.w * scale + pw * f[j].w;
            m   = mn;
        }
    }
    if (lane32 == 0) { pm[wg * H + h] = m; pl[wg * H + h] = l; }
    ((float4*)pf)[(size_t)wg * (C / 4) + t] = a;
}

// ---------------------------------------------------------------------------
// k3: per (b,h): combine NC chunk partials -> normalized fbar[128],
// then ctx[b,h,e] = sum_d fbar[d]*Wv[e,d] + bv[e].
// ---------------------------------------------------------------------------
__global__ __launch_bounds__(128) void k3_combine(
    const float* __restrict__ pm, const float* __restrict__ pl,
    const float* __restrict__ pf, const float* __restrict__ Wv,
    const float* __restrict__ bv, float* __restrict__ ctx) {
    int bh = blockIdx.x;             // b*H + h
    int b = bh >> 3, h = bh & 7;
    int t = threadIdx.x;             // 0..127
    __shared__ float wsh[NC];
    __shared__ float fsh[HD];

    float M = -1e30f;
#pragma unroll 8
    for (int i = 0; i < NC; ++i)
        M = fmaxf(M, pm[(b * NC + i) * H + h]);   // broadcast loads
    if (t < NC) wsh[t] = __expf(pm[(b * NC + t) * H + h] - M);
    __syncthreads();
    float L = 0.f;
#pragma unroll 8
    for (int i = 0; i < NC; ++i)
        L += pl[(b * NC + i) * H + h] * wsh[i];
    float acc = 0.f;
#pragma unroll 8
    for (int i = 0; i < NC; ++i)
        acc += pf[(size_t)(b * NC + i) * C + h * HD + t] * wsh[i];
    fsh[t] = acc / L;
    __syncthreads();
    float s = 0.f;
#pragma unroll 8
    for (int d = 0; d < HD; ++d)
        s += fsh[d] * Wv[t * HD + d];
    ctx[bh * HD + t] = s + bv[t];
}

// ---------------------------------------------------------------------------
// k4: out[b,s,c] = features[b,s,c] + ctx[b,c]   (grid-stride float4 stream)
// ---------------------------------------------------------------------------
__global__ __launch_bounds__(256) void k4_epilogue(
    const float* __restrict__ feat, const float* __restrict__ ctx,
    float* __restrict__ out) {
    constexpr int N4 = B * S * C / 4;            // 8388608
    int tid = blockIdx.x * 256 + threadIdx.x;
    int nth = gridDim.x * 256;
    for (int i = tid; i < N4; i += nth) {
        float4 f = ((const float4*)feat)[i];
        int b  = i >> 19;                        // / (S*C/4)
        int c4 = i & 255;                        // % (C/4)
        float4 cv = ((const float4*)ctx)[b * (C / 4) + c4];
        float4 o; o.x = f.x + cv.x; o.y = f.y + cv.y;
        o.z = f.z + cv.z; o.w = f.w + cv.w;
        ((float4*)out)[i] = o;
    }
}

extern "C" void kernel_launch(void* const* d_in, const int* in_sizes, int n_in,
                              void* d_out, int out_size, void* d_ws, size_t ws_size,
                              hipStream_t stream) {
    const float* feat = (const float*)d_in[0];
    const float* pref = (const float*)d_in[1];
    const float* Wq   = (const float*)d_in[2];
    const float* bq   = (const float*)d_in[3];
    const float* Wk   = (const float*)d_in[4];
    // d_in[5] = bk (unused: softmax shift-invariant)
    const float* Wv   = (const float*)d_in[6];
    const float* bv   = (const float*)d_in[7];
    float* out = (float*)d_out;

    float* ws  = (float*)d_ws;
    float* ctx = ws;                  // B*C          = 16384 floats
    float* pm  = ctx + B * C;         // B*NC*H       = 8192
    float* pl  = pm + B * NC * H;     // B*NC*H       = 8192
    float* pf  = pl + B * NC * H;     // B*NC*C       = 4194304

    k2_pass<<<B * NC, 256, 0, stream>>>(feat, pref, Wq, bq, Wk, pm, pl, pf);
    k3_combine<<<B * H, 128, 0, stream>>>(pm, pl, pf, Wv, bv, ctx);
    k4_epilogue<<<4096, 256, 0, stream>>>(feat, ctx, out);
}

// Round 4
// 298.322 us; speedup vs baseline: 1.0674x; 1.0674x over previous
//
#include <hip/hip_runtime.h>
#include <math.h>

#define B 16
#define S 2048
#define C 1024
#define H 8
#define HD 128
#define NC 256
#define R (S / NC)   // 8 rows per chunk

typedef float vf4 __attribute__((ext_vector_type(4)));  // native vec for nontemporal

// ---------------------------------------------------------------------------
// k1: qk[b,h,d] = sum_e q[b,h,e] * Wk[e,d],  q[b,h,e] = pref[b,h]*Wq[e]+bq[e]
// (the q·bk term is softmax-shift-invariant and dropped). Tiny: 128 blocks.
// ---------------------------------------------------------------------------
__global__ __launch_bounds__(128) void k1_qk(
    const float* __restrict__ pref, const float* __restrict__ Wq,
    const float* __restrict__ bq, const float* __restrict__ Wk,
    float* __restrict__ qk) {
    int bh = blockIdx.x;            // b*H + h
    int d  = threadIdx.x;           // 0..127
    __shared__ float qsh[HD];
    float p = pref[bh];
    qsh[d] = p * Wq[d] + bq[d];
    __syncthreads();
    float s = 0.f;
#pragma unroll 8
    for (int e = 0; e < HD; ++e)
        s += qsh[e] * Wk[e * HD + d];      // coalesced across d
    qk[bh * HD + d] = s;
}

// ---------------------------------------------------------------------------
// k2: streaming pass. Block = (b, 8-row chunk). Thread t: head h=t>>5,
// float4 column 4t. All 8 row-loads issued up front (independent, max MLP);
// 8 independent dot+butterfly reductions; then chunk-LOCAL softmax
// (max, exp, weighted accumulate) with no cross-batch serial chain.
// Partials (m_loc, l_loc, a[4]) merge exactly in k3.
// ---------------------------------------------------------------------------
__global__ __launch_bounds__(256) void k2_pass(
    const float* __restrict__ feat, const float* __restrict__ qk,
    float* __restrict__ pm, float* __restrict__ pl, float* __restrict__ pf) {
    int wg     = blockIdx.x;         // b*NC + chunk
    int b      = wg >> 8;
    int chunk  = wg & (NC - 1);
    int t      = threadIdx.x;
    int h      = t >> 5;
    int lane32 = t & 31;

    const float4* frow = (const float4*)feat
                       + (size_t)(b * S + chunk * R) * (C / 4) + t;
    float4 qv = ((const float4*)qk)[(b * H + h) * (HD / 4) + lane32];

    float4 f[R];
#pragma unroll
    for (int i = 0; i < R; ++i)
        f[i] = frow[(size_t)i * (C / 4)];        // 8 loads in flight

    float sc[R];
#pragma unroll
    for (int i = 0; i < R; ++i) {                // independent chains
        float p = f[i].x * qv.x + f[i].y * qv.y + f[i].z * qv.z + f[i].w * qv.w;
        p += __shfl_xor(p, 16, 32);
        p += __shfl_xor(p, 8, 32);
        p += __shfl_xor(p, 4, 32);
        p += __shfl_xor(p, 2, 32);
        p += __shfl_xor(p, 1, 32);
        sc[i] = p;
    }

    float M = sc[0];
#pragma unroll
    for (int i = 1; i < R; ++i) M = fmaxf(M, sc[i]);

    float l = 0.f;
    float4 a; a.x = a.y = a.z = a.w = 0.f;
#pragma unroll
    for (int i = 0; i < R; ++i) {
        float w = __expf(sc[i] - M);             // independent exps
        l   += w;
        a.x += w * f[i].x; a.y += w * f[i].y;
        a.z += w * f[i].z; a.w += w * f[i].w;
    }
    if (lane32 == 0) { pm[wg * H + h] = M; pl[wg * H + h] = l; }
    ((float4*)pf)[(size_t)wg * (C / 4) + t] = a;
}

// ---------------------------------------------------------------------------
// k3: per (b,h): merge NC chunk partials -> normalized fbar[128], then
// ctx[b,h,e] = sum_d fbar[d]*Wv[e,d] + bv[e].
// ---------------------------------------------------------------------------
__global__ __launch_bounds__(128) void k3_combine(
    const float* __restrict__ pm, const float* __restrict__ pl,
    const float* __restrict__ pf, const float* __restrict__ Wv,
    const float* __restrict__ bv, float* __restrict__ ctx) {
    int bh = blockIdx.x;             // b*H + h
    int b = bh >> 3, h = bh & 7;
    int t = threadIdx.x;             // 0..127
    __shared__ float wm[NC], wl[NC], we[NC], fsh[HD];

#pragma unroll
    for (int i = t; i < NC; i += 128) {
        wm[i] = pm[(b * NC + i) * H + h];
        wl[i] = pl[(b * NC + i) * H + h];
    }
    __syncthreads();
    float M = -1e30f;
#pragma unroll 8
    for (int i = 0; i < NC; ++i) M = fmaxf(M, wm[i]);   // redundant, cheap
#pragma unroll
    for (int i = t; i < NC; i += 128) we[i] = __expf(wm[i] - M);
    __syncthreads();
    float L = 0.f;
#pragma unroll 8
    for (int i = 0; i < NC; ++i) L += wl[i] * we[i];
    float acc = 0.f;
#pragma unroll 8
    for (int i = 0; i < NC; ++i)
        acc += we[i] * pf[(size_t)(b * NC + i) * C + h * HD + t]; // coalesced
    fsh[t] = acc / L;
    __syncthreads();
    float s = 0.f;
#pragma unroll 8
    for (int d = 0; d < HD; ++d)
        s += fsh[d] * Wv[t * HD + d];
    ctx[bh * HD + t] = s + bv[t];
}

// ---------------------------------------------------------------------------
// k4: out[b,s,c] = features[b,s,c] + ctx[b,c]. Grid-stride float4 stream;
// nontemporal store keeps features resident in L3.
// ---------------------------------------------------------------------------
__global__ __launch_bounds__(256) void k4_epilogue(
    const float* __restrict__ feat, const float* __restrict__ ctx,
    float* __restrict__ out) {
    constexpr int N4 = B * S * C / 4;            // 8388608
    int tid = blockIdx.x * 256 + threadIdx.x;
    int nth = gridDim.x * 256;
    for (int i = tid; i < N4; i += nth) {
        vf4 f = __builtin_nontemporal_load((const vf4*)feat + i);
        int b  = i >> 19;                        // / (S*C/4)
        int c4 = i & 255;                        // % (C/4)
        vf4 cv = *((const vf4*)ctx + b * (C / 4) + c4);
        vf4 o = f + cv;
        __builtin_nontemporal_store(o, (vf4*)out + i);
    }
}

extern "C" void kernel_launch(void* const* d_in, const int* in_sizes, int n_in,
                              void* d_out, int out_size, void* d_ws, size_t ws_size,
                              hipStream_t stream) {
    const float* feat = (const float*)d_in[0];
    const float* pref = (const float*)d_in[1];
    const float* Wq   = (const float*)d_in[2];
    const float* bq   = (const float*)d_in[3];
    const float* Wk   = (const float*)d_in[4];
    // d_in[5] = bk (unused: softmax shift-invariant)
    const float* Wv   = (const float*)d_in[6];
    const float* bv   = (const float*)d_in[7];
    float* out = (float*)d_out;

    float* ws  = (float*)d_ws;
    float* qk  = ws;                  // B*H*HD       = 16384 floats
    float* ctx = qk + B * H * HD;     // B*C          = 16384
    float* pm  = ctx + B * C;         // B*NC*H       = 32768
    float* pl  = pm + B * NC * H;     // B*NC*H       = 32768
    float* pf  = pl + B * NC * H;     // B*NC*C       = 4194304 (16.8 MB)

    k1_qk<<<B * H, 128, 0, stream>>>(pref, Wq, bq, Wk, qk);
    k2_pass<<<B * NC, 256, 0, stream>>>(feat, qk, pm, pl, pf);
    k3_combine<<<B * H, 128, 0, stream>>>(pm, pl, pf, Wv, bv, ctx);
    k4_epilogue<<<4096, 256, 0, stream>>>(feat, ctx, out);
}